// Round 1
// baseline (1747.956 us; speedup 1.0000x reference)
//
#include <hip/hip_runtime.h>
#include <hip/hip_bf16.h>

#define IN_FEATS 128
#define OUT_FEATS 64

// ---------------- degree accumulation ----------------
__global__ void deg_kernel(const int* __restrict__ src, const int* __restrict__ dst,
                           float* __restrict__ degS, float* __restrict__ degD, int E) {
    int e = blockIdx.x * blockDim.x + threadIdx.x;
    if (e < E) {
        atomicAdd(&degS[src[e]], 1.0f);
        atomicAdd(&degD[dst[e]], 1.0f);
    }
}

// in-place deg -> rsqrt(max(deg,1))
__global__ void norm_kernel(float* __restrict__ degS, float* __restrict__ degD, int N) {
    int i = blockIdx.x * blockDim.x + threadIdx.x;
    if (i < N) {
        degS[i] = rsqrtf(fmaxf(degS[i], 1.0f));
        degD[i] = rsqrtf(fmaxf(degD[i], 1.0f));
    }
}

// ---------------- projection Y = X @ W  (N x 128 @ 128 x 64) ----------------
// block = 256 threads = 4 nodes x 64 out-feats; W staged in LDS (32 KiB)
__global__ void proj_kernel(const float* __restrict__ X, const float* __restrict__ W,
                            float* __restrict__ Y, int N) {
    __shared__ float w_s[IN_FEATS * OUT_FEATS];
    for (int i = threadIdx.x; i < IN_FEATS * OUT_FEATS; i += 256) w_s[i] = W[i];
    __syncthreads();
    int node = blockIdx.x * 4 + (threadIdx.x >> 6);
    int j = threadIdx.x & 63;
    if (node >= N) return;
    const float* __restrict__ xr = X + (size_t)node * IN_FEATS;
    float acc = 0.0f;
#pragma unroll
    for (int k = 0; k < IN_FEATS; ++k) acc = fmaf(xr[k], w_s[k * OUT_FEATS + j], acc);
    Y[(size_t)node * OUT_FEATS + j] = acc;
}

// ---------------- scatter hop: Yout[dst] += (scale? s[src]:1) * Yin[src] ----------------
// 16 threads per edge, each thread handles 4 consecutive floats (float4 gather)
template <bool SCALED>
__global__ void hop_kernel(const float* __restrict__ Yin, const int* __restrict__ src,
                           const int* __restrict__ dst, float* __restrict__ Yout,
                           const float* __restrict__ scale, int E) {
    int t = blockIdx.x * blockDim.x + threadIdx.x;
    int e = t >> 4;
    if (e >= E) return;
    int q = (t & 15) * 4;
    int s = src[e];
    int d = dst[e];
    float4 v = *reinterpret_cast<const float4*>(Yin + (size_t)s * OUT_FEATS + q);
    if (SCALED) {
        float sc = scale[s];
        v.x *= sc; v.y *= sc; v.z *= sc; v.w *= sc;
    }
    float* __restrict__ o = Yout + (size_t)d * OUT_FEATS + q;
    atomicAdd(o + 0, v.x);
    atomicAdd(o + 1, v.y);
    atomicAdd(o + 2, v.z);
    atomicAdd(o + 3, v.w);
}

// ---------------- finalize: out = out * normD[row] + bias[col] ----------------
__global__ void finalize_kernel(float* __restrict__ out, const float* __restrict__ normD,
                                const float* __restrict__ bias, int N) {
    int t = blockIdx.x * blockDim.x + threadIdx.x;
    int i = t >> 6;
    int j = t & 63;
    if (i < N) out[t] = out[t] * normD[i] + bias[j];
}

extern "C" void kernel_launch(void* const* d_in, const int* in_sizes, int n_in,
                              void* d_out, int out_size, void* d_ws, size_t ws_size,
                              hipStream_t stream) {
    const float* features = (const float*)d_in[0];
    const int*   src      = (const int*)d_in[1];
    const int*   dst      = (const int*)d_in[2];
    const float* weight   = (const float*)d_in[3];
    const float* bias     = (const float*)d_in[4];

    const int N = in_sizes[0] / IN_FEATS;   // 50000
    const int E = in_sizes[1];              // 640000

    float* ws    = (float*)d_ws;
    float* normS = ws;                       // N
    float* normD = ws + N;                   // N
    float* y0    = ws + 2 * (size_t)N;       // N*64
    float* y1    = y0 + (size_t)N * OUT_FEATS; // N*64

    float* out = (float*)d_out;

    // zero accumulation targets (graph-capture-safe async memsets)
    hipMemsetAsync(normS, 0, sizeof(float) * N, stream);
    hipMemsetAsync(normD, 0, sizeof(float) * N, stream);
    hipMemsetAsync(y1,    0, sizeof(float) * (size_t)N * OUT_FEATS, stream);
    hipMemsetAsync(out,   0, sizeof(float) * (size_t)N * OUT_FEATS, stream);

    // degrees -> norms
    deg_kernel<<<(E + 255) / 256, 256, 0, stream>>>(src, dst, normS, normD, E);
    norm_kernel<<<(N + 255) / 256, 256, 0, stream>>>(normS, normD, N);

    // projection first (A and W commute): y0 = X @ W
    proj_kernel<<<(N + 3) / 4, 256, 0, stream>>>(features, weight, y0, N);

    const int hop_threads = E * 16;
    const int hop_blocks  = (hop_threads + 255) / 256;

    // hop 1: y1 = A y0
    hop_kernel<false><<<hop_blocks, 256, 0, stream>>>(y0, src, dst, y1, nullptr, E);

    // hop 2: y0 = A y1  (zero y0 after it has been consumed)
    hipMemsetAsync(y0, 0, sizeof(float) * (size_t)N * OUT_FEATS, stream);
    hop_kernel<false><<<hop_blocks, 256, 0, stream>>>(y1, src, dst, y0, nullptr, E);

    // hop 3: out = A (norm_src * y0)
    hop_kernel<true><<<hop_blocks, 256, 0, stream>>>(y0, src, dst, out, normS, E);

    // out = out * normD + bias
    finalize_kernel<<<((size_t)N * OUT_FEATS + 255) / 256, 256, 0, stream>>>(out, normD, bias, N);
}

// Round 2
// 372.023 us; speedup vs baseline: 4.6985x; 4.6985x over previous
//
#include <hip/hip_runtime.h>
#include <hip/hip_bf16.h>

#define IN_FEATS 128
#define OUT_FEATS 64
#define SCAN_THREADS 1024

// ---------------- degree counting (int atomics, cheap) ----------------
__global__ void count_kernel(const int* __restrict__ src, const int* __restrict__ dst,
                             int* __restrict__ cntS, int* __restrict__ cntD, int E) {
    int e = blockIdx.x * blockDim.x + threadIdx.x;
    if (e < E) {
        atomicAdd(&cntS[src[e]], 1);
        atomicAdd(&cntD[dst[e]], 1);
    }
}

// ---------------- single-block exclusive scan of cntD -> rowptr[N+1] ----------------
__global__ void scan_kernel(const int* __restrict__ cnt, int* __restrict__ rowptr, int N) {
    __shared__ int buf[SCAN_THREADS];
    __shared__ int carry;
    if (threadIdx.x == 0) carry = 0;
    __syncthreads();
    for (int base = 0; base < N; base += SCAN_THREADS) {
        int i = base + (int)threadIdx.x;
        int v = (i < N) ? cnt[i] : 0;
        buf[threadIdx.x] = v;
        __syncthreads();
        // Hillis-Steele inclusive scan
        for (int off = 1; off < SCAN_THREADS; off <<= 1) {
            int t = (threadIdx.x >= (unsigned)off) ? buf[threadIdx.x - off] : 0;
            __syncthreads();
            buf[threadIdx.x] += t;
            __syncthreads();
        }
        int incl = buf[threadIdx.x];
        if (i < N) rowptr[i] = carry + incl - v;  // exclusive
        __syncthreads();
        if (threadIdx.x == SCAN_THREADS - 1) carry += incl;
        __syncthreads();
    }
    if (threadIdx.x == 0) rowptr[N] = carry;
}

// ---------------- norms from counts + cursor init ----------------
__global__ void norm_init_kernel(const int* __restrict__ cntS, const int* __restrict__ cntD,
                                 const int* __restrict__ rowptr, float* __restrict__ normS,
                                 float* __restrict__ normD, int* __restrict__ cursor, int N) {
    int i = blockIdx.x * blockDim.x + threadIdx.x;
    if (i < N) {
        normS[i] = rsqrtf(fmaxf((float)cntS[i], 1.0f));
        normD[i] = rsqrtf(fmaxf((float)cntD[i], 1.0f));
        cursor[i] = rowptr[i];
    }
}

// ---------------- CSR bucket fill (by dst) ----------------
__global__ void fill_kernel(const int* __restrict__ src, const int* __restrict__ dst,
                            int* __restrict__ cursor, int* __restrict__ csr_src, int E) {
    int e = blockIdx.x * blockDim.x + threadIdx.x;
    if (e < E) {
        int d = dst[e];
        int pos = atomicAdd(&cursor[d], 1);
        csr_src[pos] = src[e];
    }
}

// ---------------- projection Y = X @ W  (N x 128 @ 128 x 64) ----------------
__global__ void proj_kernel(const float* __restrict__ X, const float* __restrict__ W,
                            float* __restrict__ Y, int N) {
    __shared__ float w_s[IN_FEATS * OUT_FEATS];
    for (int i = threadIdx.x; i < IN_FEATS * OUT_FEATS; i += 256) w_s[i] = W[i];
    __syncthreads();
    int node = blockIdx.x * 4 + (threadIdx.x >> 6);
    int j = threadIdx.x & 63;
    if (node >= N) return;
    const float* __restrict__ xr = X + (size_t)node * IN_FEATS;
    float acc = 0.0f;
#pragma unroll
    for (int k = 0; k < IN_FEATS; ++k) acc = fmaf(xr[k], w_s[k * OUT_FEATS + j], acc);
    Y[(size_t)node * OUT_FEATS + j] = acc;
}

// ---------------- gather hop: Yout[i] = epi( sum_{e: dst=i} Yin[src_e] ) ----------------
// one wave per node: 64 lanes = 64 feature columns; coalesced 256B row reads, plain store
// EPI: 0 = none, 1 = *vec[i], 2 = *vec[i] + bias[j]
template <int EPI>
__global__ void gather_hop(const float* __restrict__ Yin, const int* __restrict__ rowptr,
                           const int* __restrict__ csr_src, float* __restrict__ Yout,
                           const float* __restrict__ vec, const float* __restrict__ bias,
                           int N) {
    int node = blockIdx.x * 4 + (threadIdx.x >> 6);
    int j = threadIdx.x & 63;
    if (node >= N) return;
    int beg = rowptr[node];
    int end = rowptr[node + 1];
    float acc0 = 0.0f, acc1 = 0.0f;
    int k = beg;
    for (; k + 1 < end; k += 2) {
        int s0 = csr_src[k];
        int s1 = csr_src[k + 1];
        acc0 += Yin[(size_t)s0 * OUT_FEATS + j];
        acc1 += Yin[(size_t)s1 * OUT_FEATS + j];
    }
    if (k < end) acc0 += Yin[(size_t)csr_src[k] * OUT_FEATS + j];
    float acc = acc0 + acc1;
    if (EPI == 1) acc *= vec[node];
    if (EPI == 2) acc = acc * vec[node] + bias[j];
    Yout[(size_t)node * OUT_FEATS + j] = acc;
}

extern "C" void kernel_launch(void* const* d_in, const int* in_sizes, int n_in,
                              void* d_out, int out_size, void* d_ws, size_t ws_size,
                              hipStream_t stream) {
    const float* features = (const float*)d_in[0];
    const int*   src      = (const int*)d_in[1];
    const int*   dst      = (const int*)d_in[2];
    const float* weight   = (const float*)d_in[3];
    const float* bias     = (const float*)d_in[4];

    const int N = in_sizes[0] / IN_FEATS;   // 50000
    const int E = in_sizes[1];              // 640000

    // workspace layout
    char* p = (char*)d_ws;
    float* normS  = (float*)p;                 p += sizeof(float) * N;
    float* normD  = (float*)p;                 p += sizeof(float) * N;
    float* y0     = (float*)p;                 p += sizeof(float) * (size_t)N * OUT_FEATS;
    float* y1     = (float*)p;                 p += sizeof(float) * (size_t)N * OUT_FEATS;
    int*   cntS   = (int*)p;                   p += sizeof(int) * N;
    int*   cntD   = (int*)p;                   p += sizeof(int) * N;
    int*   rowptr = (int*)p;                   p += sizeof(int) * (N + 1);
    int*   cursor = (int*)p;                   p += sizeof(int) * N;
    int*   csr_src= (int*)p;                   p += sizeof(int) * (size_t)E;

    float* out = (float*)d_out;

    // zero only the count arrays (gathers fully overwrite outputs)
    hipMemsetAsync(cntS, 0, sizeof(int) * N, stream);
    hipMemsetAsync(cntD, 0, sizeof(int) * N, stream);

    // --- CSR build + norms ---
    count_kernel<<<(E + 255) / 256, 256, 0, stream>>>(src, dst, cntS, cntD, E);
    scan_kernel<<<1, SCAN_THREADS, 0, stream>>>(cntD, rowptr, N);
    norm_init_kernel<<<(N + 255) / 256, 256, 0, stream>>>(cntS, cntD, rowptr, normS, normD, cursor, N);
    fill_kernel<<<(E + 255) / 256, 256, 0, stream>>>(src, dst, cursor, csr_src, E);

    // --- projection first (A and W commute): y0 = X @ W ---
    proj_kernel<<<(N + 3) / 4, 256, 0, stream>>>(features, weight, y0, N);

    const int hop_blocks = (N + 3) / 4;

    // hop 1: y1 = A y0
    gather_hop<0><<<hop_blocks, 256, 0, stream>>>(y0, rowptr, csr_src, y1, nullptr, nullptr, N);
    // hop 2: y0 = normS .* (A y1)
    gather_hop<1><<<hop_blocks, 256, 0, stream>>>(y1, rowptr, csr_src, y0, normS, nullptr, N);
    // hop 3: out = normD .* (A y0) + bias
    gather_hop<2><<<hop_blocks, 256, 0, stream>>>(y0, rowptr, csr_src, out, normD, bias, N);
}

// Round 3
// 222.035 us; speedup vs baseline: 7.8725x; 1.6755x over previous
//
#include <hip/hip_runtime.h>
#include <hip/hip_bf16.h>

#define IN_FEATS 128
#define OUT_FEATS 64
#define CHUNK 1024   // elements per scan block (256 threads x int4)

static inline char* align_up(char* p, size_t a) {
    return (char*)(((uintptr_t)p + a - 1) & ~(uintptr_t)(a - 1));
}

// ---------------- degree counting (int atomics, cheap) ----------------
__global__ void count_kernel(const int* __restrict__ src, const int* __restrict__ dst,
                             int* __restrict__ cntS, int* __restrict__ cntD, int E) {
    int e = blockIdx.x * blockDim.x + threadIdx.x;
    if (e < E) {
        atomicAdd(&cntS[src[e]], 1);
        atomicAdd(&cntD[dst[e]], 1);
    }
}

// ---------------- scan phase 1: per-block partial sums of cntD ----------------
__global__ void scan_partial(const int* __restrict__ cnt, int* __restrict__ blockSums, int N) {
    __shared__ int red[256];
    int base = blockIdx.x * CHUNK + (int)threadIdx.x * 4;
    int s = 0;
    if (base + 3 < N) {
        int4 v = *reinterpret_cast<const int4*>(cnt + base);
        s = v.x + v.y + v.z + v.w;
    } else {
        for (int i = 0; i < 4; ++i) { int idx = base + i; if (idx < N) s += cnt[idx]; }
    }
    red[threadIdx.x] = s;
    __syncthreads();
    for (int off = 128; off > 0; off >>= 1) {
        if ((int)threadIdx.x < off) red[threadIdx.x] += red[threadIdx.x + off];
        __syncthreads();
    }
    if (threadIdx.x == 0) blockSums[blockIdx.x] = red[0];
}

// ---------------- scan phase 2: one wave scans the block sums ----------------
__global__ void scan_sums(const int* __restrict__ bs, int* __restrict__ boff,
                          int NB, int* __restrict__ rowptr, int N) {
    int lane = threadIdx.x;
    int carry = 0;
    for (int base = 0; base < NB; base += 64) {
        int i = base + lane;
        int orig = (i < NB) ? bs[i] : 0;
        int v = orig;
        for (int off = 1; off < 64; off <<= 1) {
            int t = __shfl_up(v, off);
            if (lane >= off) v += t;
        }
        if (i < NB) boff[i] = carry + v - orig;  // exclusive offset for block i
        carry += __shfl(v, 63);
    }
    if (lane == 0) rowptr[N] = carry;
}

// ---------------- scan phase 3: apply + fused norms/cursor init ----------------
__global__ void scan_apply(const int* __restrict__ cntD, const int* __restrict__ cntS,
                           const int* __restrict__ boff, int* __restrict__ rowptr,
                           int* __restrict__ cursor, float* __restrict__ normS,
                           float* __restrict__ normD, int N) {
    __shared__ int tsum[256];
    int tid = threadIdx.x;
    int base = blockIdx.x * CHUNK + tid * 4;
    int4 c = make_int4(0, 0, 0, 0);
    bool full = (base + 3 < N);
    if (full) {
        c = *reinterpret_cast<const int4*>(cntD + base);
    } else {
        if (base + 0 < N) c.x = cntD[base + 0];
        if (base + 1 < N) c.y = cntD[base + 1];
        if (base + 2 < N) c.z = cntD[base + 2];
        if (base + 3 < N) c.w = cntD[base + 3];
    }
    int s = c.x + c.y + c.z + c.w;
    tsum[tid] = s;
    __syncthreads();
    // Hillis-Steele inclusive scan over 256 thread-sums
    for (int off = 1; off < 256; off <<= 1) {
        int t = (tid >= off) ? tsum[tid - off] : 0;
        __syncthreads();
        tsum[tid] += t;
        __syncthreads();
    }
    int excl = tsum[tid] - s + boff[blockIdx.x];
    int r0 = excl, r1 = r0 + c.x, r2 = r1 + c.y, r3 = r2 + c.z;
    if (full) {
        *reinterpret_cast<int4*>(rowptr + base) = make_int4(r0, r1, r2, r3);
        *reinterpret_cast<int4*>(cursor + base) = make_int4(r0, r1, r2, r3);
        int4 cs = *reinterpret_cast<const int4*>(cntS + base);
        float4 nS = make_float4(rsqrtf(fmaxf((float)cs.x, 1.0f)), rsqrtf(fmaxf((float)cs.y, 1.0f)),
                                rsqrtf(fmaxf((float)cs.z, 1.0f)), rsqrtf(fmaxf((float)cs.w, 1.0f)));
        float4 nD = make_float4(rsqrtf(fmaxf((float)c.x, 1.0f)), rsqrtf(fmaxf((float)c.y, 1.0f)),
                                rsqrtf(fmaxf((float)c.z, 1.0f)), rsqrtf(fmaxf((float)c.w, 1.0f)));
        *reinterpret_cast<float4*>(normS + base) = nS;
        *reinterpret_cast<float4*>(normD + base) = nD;
    } else {
        int r[4] = {r0, r1, r2, r3};
        for (int i = 0; i < 4; ++i) {
            int idx = base + i;
            if (idx < N) {
                rowptr[idx] = r[i];
                cursor[idx] = r[i];
                normS[idx] = rsqrtf(fmaxf((float)cntS[idx], 1.0f));
                int cd = (i == 0) ? c.x : (i == 1) ? c.y : (i == 2) ? c.z : c.w;
                normD[idx] = rsqrtf(fmaxf((float)cd, 1.0f));
            }
        }
    }
}

// ---------------- CSR bucket fill (by dst) ----------------
__global__ void fill_kernel(const int* __restrict__ src, const int* __restrict__ dst,
                            int* __restrict__ cursor, int* __restrict__ csr_src, int E) {
    int e = blockIdx.x * blockDim.x + threadIdx.x;
    if (e < E) {
        int d = dst[e];
        int pos = atomicAdd(&cursor[d], 1);
        csr_src[pos] = src[e];
    }
}

// ---------------- projection Y = X @ W  (N x 128 @ 128 x 64) ----------------
// block = 256 = 16 nodes x 16 lanes; each lane owns 4 consecutive out-feats.
// W staged in LDS; per k: broadcast x + one ds_read_b128 per lane (~2-way, free).
__global__ void proj_kernel(const float* __restrict__ X, const float* __restrict__ W,
                            float* __restrict__ Y, int N) {
    __shared__ float w_s[IN_FEATS * OUT_FEATS];
    for (int i = threadIdx.x; i < IN_FEATS * OUT_FEATS; i += 256) w_s[i] = W[i];
    __syncthreads();
    int node = blockIdx.x * 16 + ((int)threadIdx.x >> 4);
    int jj = ((int)threadIdx.x & 15) * 4;
    if (node >= N) return;
    const float* __restrict__ xr = X + (size_t)node * IN_FEATS;
    float4 acc = make_float4(0.f, 0.f, 0.f, 0.f);
#pragma unroll
    for (int k = 0; k < IN_FEATS; ++k) {
        float x = xr[k];
        float4 w = *reinterpret_cast<const float4*>(&w_s[k * OUT_FEATS + jj]);
        acc.x = fmaf(x, w.x, acc.x);
        acc.y = fmaf(x, w.y, acc.y);
        acc.z = fmaf(x, w.z, acc.z);
        acc.w = fmaf(x, w.w, acc.w);
    }
    *reinterpret_cast<float4*>(&Y[(size_t)node * OUT_FEATS + jj]) = acc;
}

// ---------------- gather hop: Yout[i] = epi( sum_{e: dst=i} Yin[src_e] ) ----------------
// one wave per node: 64 lanes = 64 feature columns; 4-way unroll for MLP.
// EPI: 0 = none, 1 = *vec[i], 2 = *vec[i] + bias[j]
template <int EPI>
__global__ void gather_hop(const float* __restrict__ Yin, const int* __restrict__ rowptr,
                           const int* __restrict__ csr_src, float* __restrict__ Yout,
                           const float* __restrict__ vec, const float* __restrict__ bias,
                           int N) {
    int node = blockIdx.x * 4 + ((int)threadIdx.x >> 6);
    int j = (int)threadIdx.x & 63;
    if (node >= N) return;
    int beg = rowptr[node];
    int end = rowptr[node + 1];
    float acc0 = 0.f, acc1 = 0.f, acc2 = 0.f, acc3 = 0.f;
    int k = beg;
    for (; k + 3 < end; k += 4) {
        int s0 = csr_src[k];
        int s1 = csr_src[k + 1];
        int s2 = csr_src[k + 2];
        int s3 = csr_src[k + 3];
        acc0 += Yin[(size_t)s0 * OUT_FEATS + j];
        acc1 += Yin[(size_t)s1 * OUT_FEATS + j];
        acc2 += Yin[(size_t)s2 * OUT_FEATS + j];
        acc3 += Yin[(size_t)s3 * OUT_FEATS + j];
    }
    for (; k < end; ++k) acc0 += Yin[(size_t)csr_src[k] * OUT_FEATS + j];
    float acc = (acc0 + acc1) + (acc2 + acc3);
    if (EPI == 1) acc *= vec[node];
    if (EPI == 2) acc = acc * vec[node] + bias[j];
    Yout[(size_t)node * OUT_FEATS + j] = acc;
}

extern "C" void kernel_launch(void* const* d_in, const int* in_sizes, int n_in,
                              void* d_out, int out_size, void* d_ws, size_t ws_size,
                              hipStream_t stream) {
    const float* features = (const float*)d_in[0];
    const int*   src      = (const int*)d_in[1];
    const int*   dst      = (const int*)d_in[2];
    const float* weight   = (const float*)d_in[3];
    const float* bias     = (const float*)d_in[4];

    const int N = in_sizes[0] / IN_FEATS;   // 50000
    const int E = in_sizes[1];              // 640000
    const int NB = (N + CHUNK - 1) / CHUNK; // scan blocks (49)

    // workspace layout (256B-aligned slabs)
    char* p = (char*)d_ws;
    float* normS   = (float*)p;  p = align_up(p + sizeof(float) * N, 256);
    float* normD   = (float*)p;  p = align_up(p + sizeof(float) * N, 256);
    float* y0      = (float*)p;  p = align_up(p + sizeof(float) * (size_t)N * OUT_FEATS, 256);
    float* y1      = (float*)p;  p = align_up(p + sizeof(float) * (size_t)N * OUT_FEATS, 256);
    int*   cntS    = (int*)p;    p = align_up(p + sizeof(int) * N, 256);
    int*   cntD    = (int*)p;    p = align_up(p + sizeof(int) * N, 256);
    int*   rowptr  = (int*)p;    p = align_up(p + sizeof(int) * (N + 1), 256);
    int*   cursor  = (int*)p;    p = align_up(p + sizeof(int) * N, 256);
    int*   bsums   = (int*)p;    p = align_up(p + sizeof(int) * NB, 256);
    int*   boff    = (int*)p;    p = align_up(p + sizeof(int) * NB, 256);
    int*   csr_src = (int*)p;    p = align_up(p + sizeof(int) * (size_t)E, 256);

    float* out = (float*)d_out;

    // zero only the count arrays (gathers fully overwrite outputs)
    hipMemsetAsync(cntS, 0, sizeof(int) * N, stream);
    hipMemsetAsync(cntD, 0, sizeof(int) * N, stream);

    // --- CSR build + norms (parallel 3-phase scan, phase 3 fuses norm/cursor init) ---
    count_kernel<<<(E + 255) / 256, 256, 0, stream>>>(src, dst, cntS, cntD, E);
    scan_partial<<<NB, 256, 0, stream>>>(cntD, bsums, N);
    scan_sums<<<1, 64, 0, stream>>>(bsums, boff, NB, rowptr, N);
    scan_apply<<<NB, 256, 0, stream>>>(cntD, cntS, boff, rowptr, cursor, normS, normD, N);
    fill_kernel<<<(E + 255) / 256, 256, 0, stream>>>(src, dst, cursor, csr_src, E);

    // --- projection first (A and W commute): y0 = X @ W ---
    proj_kernel<<<(N + 15) / 16, 256, 0, stream>>>(features, weight, y0, N);

    const int hop_blocks = (N + 3) / 4;

    // hop 1: y1 = A y0
    gather_hop<0><<<hop_blocks, 256, 0, stream>>>(y0, rowptr, csr_src, y1, nullptr, nullptr, N);
    // hop 2: y0 = normS .* (A y1)
    gather_hop<1><<<hop_blocks, 256, 0, stream>>>(y1, rowptr, csr_src, y0, normS, nullptr, N);
    // hop 3: out = normD .* (A y0) + bias
    gather_hop<2><<<hop_blocks, 256, 0, stream>>>(y0, rowptr, csr_src, out, normD, bias, N);
}